// Round 1
// baseline (383.949 us; speedup 1.0000x reference)
//
#include <hip/hip_runtime.h>
#include <stdint.h>

typedef unsigned short u16;
typedef __attribute__((ext_vector_type(4))) float f32x4;
typedef __attribute__((ext_vector_type(8))) short s16x8;

#define BATCH 4
#define SEQ   2048
#define DIM   1024   // D_IN = STATE = D_OUT
#define KX    10
#define NROW  (BATCH*SEQ)      // 8192
#define PAD   16               // zero rows per batch for AR lags
#define SEQP  (SEQ+PAD)        // 2064

// fp32 -> bf16 round-to-nearest-even
__device__ __forceinline__ u16 f2b(float f) {
    union { float f; uint32_t u; } v; v.f = f;
    uint32_t u = v.u + 0x7fffu + ((v.u >> 16) & 1u);
    return (u16)(u >> 16);
}

// async global->LDS, 16B per lane; lds dest must be wave-uniform base (+lane*16 by HW)
__device__ __forceinline__ void llds16(const u16* g, u16* l) {
    __builtin_amdgcn_global_load_lds(
        (const __attribute__((address_space(1))) uint32_t*)g,
        (__attribute__((address_space(3))) uint32_t*)l, 16, 0, 0);
}

// ---------------- conversion kernels ----------------

// inputs (4,2048,1024) f32 -> Xpad (4,2064,1024) bf16 with 16 leading zero rows per batch
__global__ void k_conv_x(const float* __restrict__ x, u16* __restrict__ xp) {
    int idx = blockIdx.x * 256 + threadIdx.x;       // one thread = 4 elements
    long e = (long)idx * 4;
    int i = (int)(e & 1023);
    int row = (int)(e >> 10);                        // 0 .. 4*2064-1
    int t = row % SEQP;
    int b = row / SEQP;
    ushort4 o;
    if (t < PAD) {
        o.x = 0; o.y = 0; o.z = 0; o.w = 0;
    } else {
        const float4 v = *(const float4*)(x + (((long)(b * SEQ + (t - PAD)) << 10) + i));
        o.x = f2b(v.x); o.y = f2b(v.y); o.z = f2b(v.z); o.w = f2b(v.w);
    }
    *(ushort4*)(xp + ((long)row << 10) + i) = o;
}

// out[c][r] = bf16(in[r][c]) for 1024x1024
__global__ void k_transpose_bf(const float* __restrict__ in, u16* __restrict__ out) {
    __shared__ float tile[32][33];
    int bx = blockIdx.x, by = blockIdx.y;
    int tx = threadIdx.x, ty = threadIdx.y;          // (32, 8)
#pragma unroll
    for (int j = 0; j < 4; j++)
        tile[ty + j * 8][tx] = in[(long)(by * 32 + ty + j * 8) * 1024 + bx * 32 + tx];
    __syncthreads();
#pragma unroll
    for (int j = 0; j < 4; j++)
        out[(long)(bx * 32 + ty + j * 8) * 1024 + by * 32 + tx] = f2b(tile[tx][ty + j * 8]);
}

// M (o,i,k) f32 -> Wall groups 1..10 as [k][o][i] bf16
__global__ void k_conv_m(const float* __restrict__ M, u16* __restrict__ Wall) {
    int idx = blockIdx.x * 256 + threadIdx.x;        // o*1024 + i
    int o = idx >> 10, i = idx & 1023;
    const float* src = M + (long)idx * KX;           // (o*1024+i)*10
#pragma unroll
    for (int k = 0; k < KX; k++)
        Wall[((long)(k + 1) << 20) + ((long)o << 10) + i] = f2b(src[k]);
}

// ---------------- scan kernels (chunked parallel linear scan) ----------------
// chunks: 16 per batch, 128 steps each

__global__ void k_scan1(const float* __restrict__ U, const float* __restrict__ A,
                        float* __restrict__ F) {
    int s = blockIdx.x * 256 + threadIdx.x;          // 0..1023 (grid.x = 4)
    int bc = blockIdx.y;                             // b*16 + c  (grid.y = 64)
    int b = bc >> 4, c = bc & 15;
    float a = A[s];
    const float* u = U + (((long)(b * SEQ + c * 128)) << 10) + s;
    float f = 0.f;
#pragma unroll 8
    for (int j = 0; j < 128; j++) f = fmaf(a, f, u[(long)j << 10]);
    F[((long)bc << 10) + s] = f;
}

__global__ void k_scan2(const float* __restrict__ F, const float* __restrict__ A,
                        const float* __restrict__ h0, float* __restrict__ Carry) {
    int idx = blockIdx.x * 256 + threadIdx.x;        // 0..4095
    int b = idx >> 10, s = idx & 1023;
    float a = A[s];
    float a128 = a;
#pragma unroll
    for (int q = 0; q < 7; q++) a128 *= a128;        // a^128
    float carry = h0[s];
#pragma unroll
    for (int c = 0; c < 16; c++) {
        long off = ((long)(b * 16 + c) << 10) + s;
        Carry[off] = carry;
        carry = fmaf(a128, carry, F[off]);
    }
}

__global__ void k_scan3(const float* __restrict__ U, const float* __restrict__ A,
                        const float* __restrict__ Carry, u16* __restrict__ Hbf) {
    int s = blockIdx.x * 256 + threadIdx.x;
    int bc = blockIdx.y;
    int b = bc >> 4, c = bc & 15;
    float a = A[s];
    long base = (((long)(b * SEQ + c * 128)) << 10) + s;
    float h = Carry[((long)bc << 10) + s];
#pragma unroll 8
    for (int j = 0; j < 128; j++) {
        h = fmaf(a, h, U[base + ((long)j << 10)]);
        Hbf[base + ((long)j << 10)] = f2b(h);
    }
}

// ---------------- grouped GEMM ----------------
// out[r][n] = sum_g sum_k Aop_g[r][k] * W[g][n][k]
// group 0 (use_h): Aop = Hbf (lag 0); groups g>=1: Aop = Xpad rows shifted by lag g-1.
// W stored transposed per group: [g][n=o][k=i], bf16.
// 128x128 tile, BK=64, 4 waves in 2x2, 4x4 mfma_f32_16x16x32_bf16 per wave.
__global__ __launch_bounds__(256) void k_gemm(
    float* __restrict__ out, const u16* __restrict__ Xpad,
    const u16* __restrict__ Hbf, const u16* __restrict__ W,
    int ngroups, int use_h)
{
    __shared__ u16 At[128 * 64];
    __shared__ u16 Bt[128 * 64];

    const int tid  = threadIdx.x;
    const int wave = tid >> 6, lane = tid & 63;
    const int wm = wave >> 1, wn = wave & 1;
    const int quad = lane >> 4, l15 = lane & 15, l7 = lane & 7;

    const int col0 = blockIdx.x * 128;
    const int row0 = blockIdx.y * 128;
    const int b = row0 >> 11;                        // 2048 rows per batch, tiles don't straddle
    const long Xrow0 = (long)b * SEQP + PAD + (row0 & (SEQ - 1));

    const int s_base = wave * 256 + lane;            // staging unit id (+q*64)

    f32x4 acc[4][4];
#pragma unroll
    for (int i = 0; i < 4; i++)
#pragma unroll
        for (int j = 0; j < 4; j++)
            acc[i][j] = (f32x4){0.f, 0.f, 0.f, 0.f};

    for (int g = 0; g < ngroups; g++) {
        const u16* Ab;
        if (use_h && g == 0) {
            Ab = Hbf + ((long)row0 << 10);
        } else {
            int lag = use_h ? (g - 1) : 0;
            Ab = Xpad + ((Xrow0 - lag) << 10);
        }
        const u16* Wb = W + ((long)g << 20) + ((long)col0 << 10);

        for (int k0 = 0; k0 < 1024; k0 += 64) {
            // ---- stage A and B tiles: unit s holds (row=s>>3, kc=(s&7)^(row&7)) ----
#pragma unroll
            for (int q = 0; q < 4; q++) {
                int s = s_base + q * 64;
                int row = s >> 3;
                int kc = (s & 7) ^ (row & 7);
                const u16* gA = Ab + ((long)row << 10) + k0 + kc * 8;
                const u16* gB = Wb + ((long)row << 10) + k0 + kc * 8;
                llds16(gA, &At[(wave * 256 + q * 64) * 8]);
                llds16(gB, &Bt[(wave * 256 + q * 64) * 8]);
            }
            __syncthreads();

            // ---- fragments (swizzled ds_read_b128) ----
            s16x8 af[4][2], bfr[4][2];
#pragma unroll
            for (int mi = 0; mi < 4; mi++) {
#pragma unroll
                for (int kk = 0; kk < 2; kk++) {
                    int kcu = ((kk * 4 + quad) ^ l7) << 3;
                    af[mi][kk]  = *(const s16x8*)&At[(wm * 64 + mi * 16 + l15) * 64 + kcu];
                    bfr[mi][kk] = *(const s16x8*)&Bt[(wn * 64 + mi * 16 + l15) * 64 + kcu];
                }
            }
#pragma unroll
            for (int mi = 0; mi < 4; mi++)
#pragma unroll
                for (int ni = 0; ni < 4; ni++) {
                    acc[mi][ni] = __builtin_amdgcn_mfma_f32_16x16x32_bf16(
                        af[mi][0], bfr[ni][0], acc[mi][ni], 0, 0, 0);
                    acc[mi][ni] = __builtin_amdgcn_mfma_f32_16x16x32_bf16(
                        af[mi][1], bfr[ni][1], acc[mi][ni], 0, 0, 0);
                }
            __syncthreads();
        }
    }

    // ---- epilogue: C/D layout col=lane&15, row=quad*4+reg ----
#pragma unroll
    for (int mi = 0; mi < 4; mi++) {
        int r = row0 + wm * 64 + mi * 16 + quad * 4;
#pragma unroll
        for (int ni = 0; ni < 4; ni++) {
            int c = col0 + wn * 64 + ni * 16 + l15;
            f32x4 v = acc[mi][ni];
#pragma unroll
            for (int reg = 0; reg < 4; reg++)
                out[((long)(r + reg) << 10) + c] = v[reg];
        }
    }
}

// ---------------- launch ----------------

extern "C" void kernel_launch(void* const* d_in, const int* in_sizes, int n_in,
                              void* d_out, int out_size, void* d_ws, size_t ws_size,
                              hipStream_t stream) {
    const float* x  = (const float*)d_in[0];   // (4,2048,1024)
    const float* h0 = (const float*)d_in[1];   // (1024,)
    const float* A  = (const float*)d_in[2];   // (1024,)
    const float* B  = (const float*)d_in[3];   // (1024,1024)
    const float* C  = (const float*)d_in[4];   // (1024,1024)
    const float* M  = (const float*)d_in[5];   // (1024,1024,10)
    float* out = (float*)d_out;

    char* ws = (char*)d_ws;
    u16*   Xpad  = (u16*)  (ws);                      // 4*2064*1024*2 = 16,908,288
    u16*   Hbf   = (u16*)  (ws + 16908288);           // 16,777,216
    u16*   Wall  = (u16*)  (ws + 33685504);           // 11*1M*2 = 23,068,672 (group0 = C^T)
    u16*   Btr   = (u16*)  (ws + 56754176);           // 2,097,152
    float* U     = (float*)(ws + 58851328);           // 33,554,432
    float* F     = (float*)(ws + 92405760);           // 262,144
    float* Carry = (float*)(ws + 92667904);           // 262,144  (end ~92.9 MB)

    // conversions (independent)
    k_conv_x<<<dim3(BATCH * SEQP * DIM / 4 / 256), dim3(256), 0, stream>>>(x, Xpad);
    k_transpose_bf<<<dim3(32, 32), dim3(32, 8), 0, stream>>>(B, Btr);
    k_transpose_bf<<<dim3(32, 32), dim3(32, 8), 0, stream>>>(C, Wall);      // group 0
    k_conv_m<<<dim3(DIM * DIM / 256), dim3(256), 0, stream>>>(M, Wall);

    // U = X @ B
    k_gemm<<<dim3(8, 64), dim3(256), 0, stream>>>(U, Xpad, Xpad, Btr, 1, 0);

    // chunked linear scan -> Hbf
    k_scan1<<<dim3(4, 64), dim3(256), 0, stream>>>(U, A, F);
    k_scan2<<<dim3(16), dim3(256), 0, stream>>>(F, A, h0, Carry);
    k_scan3<<<dim3(4, 64), dim3(256), 0, stream>>>(U, A, Carry, Hbf);

    // out = H @ C + sum_k shift_k(X) @ M_k   (11 K-groups)
    k_gemm<<<dim3(8, 64), dim3(256), 0, stream>>>(out, Xpad, Hbf, Wall, 11, 1);
}

// Round 2
// 367.224 us; speedup vs baseline: 1.0455x; 1.0455x over previous
//
#include <hip/hip_runtime.h>
#include <stdint.h>

typedef unsigned short u16;
typedef __attribute__((ext_vector_type(4))) float f32x4;
typedef __attribute__((ext_vector_type(8))) short s16x8;

#define BATCH 4
#define SEQ   2048
#define DIM   1024   // D_IN = STATE = D_OUT
#define KX    10
#define PAD   16               // zero rows per batch for AR lags
#define SEQP  (SEQ+PAD)        // 2064

// fp32 -> bf16 round-to-nearest-even
__device__ __forceinline__ u16 f2b(float f) {
    union { float f; uint32_t u; } v; v.f = f;
    uint32_t u = v.u + 0x7fffu + ((v.u >> 16) & 1u);
    return (u16)(u >> 16);
}
__device__ __forceinline__ float b2f(u16 h) {
    union { uint32_t u; float f; } v; v.u = ((uint32_t)h) << 16;
    return v.f;
}

// async global->LDS, 16B per lane; lds dest is wave-uniform base (+lane*16 by HW)
__device__ __forceinline__ void llds16(const u16* g, u16* l) {
    __builtin_amdgcn_global_load_lds(
        (const __attribute__((address_space(1))) uint32_t*)g,
        (__attribute__((address_space(3))) uint32_t*)l, 16, 0, 0);
}

// ---------------- fused prep kernel ----------------
// block ranges: [0,8256) conv_x | [8256,9280) transpose B | [9280,10304) transpose C
//               | [10304,14400) conv_m
#define PREP_X_END  8256
#define PREP_B_END  9280
#define PREP_C_END  10304
#define PREP_M_END  14400

__global__ __launch_bounds__(256) void k_prep(
    const float* __restrict__ x, const float* __restrict__ B,
    const float* __restrict__ C, const float* __restrict__ M,
    u16* __restrict__ Xpad, u16* __restrict__ Btr, u16* __restrict__ Wall)
{
    __shared__ float tile[32][33];
    const int bid = blockIdx.x, tid = threadIdx.x;

    if (bid < PREP_X_END) {
        // inputs (4,2048,1024) f32 -> Xpad (4,2064,1024) bf16, 16 zero rows/batch
        int idx = bid * 256 + tid;                  // one thread = 4 elements
        long e = (long)idx * 4;
        int i = (int)(e & 1023);
        int row = (int)(e >> 10);
        int t = row % SEQP;
        int b = row / SEQP;
        ushort4 o;
        if (t < PAD) {
            o.x = 0; o.y = 0; o.z = 0; o.w = 0;
        } else {
            const float4 v = *(const float4*)(x + (((long)(b * SEQ + (t - PAD)) << 10) + i));
            o.x = f2b(v.x); o.y = f2b(v.y); o.z = f2b(v.z); o.w = f2b(v.w);
        }
        *(ushort4*)(Xpad + ((long)row << 10) + i) = o;
    } else if (bid < PREP_C_END) {
        // transpose+bf16: B -> Btr, C -> Wall group 0
        const int tb = bid - PREP_X_END;
        const float* in = (tb < 1024) ? B : C;
        u16* out = (tb < 1024) ? Btr : Wall;
        int lb = tb & 1023;
        int bx = lb & 31, by = lb >> 5;
        int tx = tid & 31, ty = tid >> 5;           // (32,8)
#pragma unroll
        for (int j = 0; j < 4; j++)
            tile[ty + j * 8][tx] = in[(long)(by * 32 + ty + j * 8) * 1024 + bx * 32 + tx];
        __syncthreads();
#pragma unroll
        for (int j = 0; j < 4; j++)
            out[(long)(bx * 32 + ty + j * 8) * 1024 + by * 32 + tx] = f2b(tile[tx][ty + j * 8]);
    } else {
        // M (o,i,k) f32 -> Wall groups 1..10 as [k][o][i] bf16
        int idx = (bid - PREP_C_END) * 256 + tid;   // o*1024 + i
        int o = idx >> 10, i = idx & 1023;
        const float* src = M + (long)idx * KX;
#pragma unroll
        for (int k = 0; k < KX; k++)
            Wall[((long)(k + 1) << 20) + ((long)o << 10) + i] = f2b(src[k]);
    }
}

// ---------------- scan kernels (chunked parallel linear scan) ----------------
// chunks: 16 per batch, 128 steps each. U is bf16.

__global__ void k_scan1(const u16* __restrict__ U, const float* __restrict__ A,
                        float* __restrict__ F) {
    int s = blockIdx.x * 256 + threadIdx.x;          // 0..1023 (grid.x = 4)
    int bc = blockIdx.y;                             // b*16 + c  (grid.y = 64)
    int b = bc >> 4, c = bc & 15;
    float a = A[s];
    const u16* u = U + (((long)(b * SEQ + c * 128)) << 10) + s;
    float f = 0.f;
#pragma unroll 8
    for (int j = 0; j < 128; j++) f = fmaf(a, f, b2f(u[(long)j << 10]));
    F[((long)bc << 10) + s] = f;
}

__global__ void k_scan2(const float* __restrict__ F, const float* __restrict__ A,
                        const float* __restrict__ h0, float* __restrict__ Carry) {
    int idx = blockIdx.x * 256 + threadIdx.x;        // 0..4095
    int b = idx >> 10, s = idx & 1023;
    float a = A[s];
    float a128 = a;
#pragma unroll
    for (int q = 0; q < 7; q++) a128 *= a128;        // a^128
    float carry = h0[s];
#pragma unroll
    for (int c = 0; c < 16; c++) {
        long off = ((long)(b * 16 + c) << 10) + s;
        Carry[off] = carry;
        carry = fmaf(a128, carry, F[off]);
    }
}

__global__ void k_scan3(const u16* __restrict__ U, const float* __restrict__ A,
                        const float* __restrict__ Carry, u16* __restrict__ Hbf) {
    int s = blockIdx.x * 256 + threadIdx.x;
    int bc = blockIdx.y;
    int b = bc >> 4, c = bc & 15;
    float a = A[s];
    long base = (((long)(b * SEQ + c * 128)) << 10) + s;
    float h = Carry[((long)bc << 10) + s];
#pragma unroll 8
    for (int j = 0; j < 128; j++) {
        h = fmaf(a, h, b2f(U[base + ((long)j << 10)]));
        Hbf[base + ((long)j << 10)] = f2b(h);
    }
}

// ---------------- grouped GEMM ----------------
// out[r][n] = sum_g sum_k Aop_g[r][k] * W[g][n][k]
// group 0 (use_h): Aop = Hbf (lag 0); groups g>=1: Aop = Xpad rows shifted by lag g-1.
// W stored transposed per group: [g][n=o][k=i], bf16.
// 128x128 tile, BK=64, 4 waves in 2x2, 4x4 mfma_f32_16x16x32_bf16 per wave.
__global__ __launch_bounds__(256) void k_gemm(
    void* __restrict__ outv, const u16* __restrict__ Xpad,
    const u16* __restrict__ Hbf, const u16* __restrict__ W,
    int ngroups, int use_h, int bf16_out)
{
    __shared__ u16 At[128 * 64];
    __shared__ u16 Bt[128 * 64];

    const int tid  = threadIdx.x;
    const int wave = tid >> 6, lane = tid & 63;
    const int wm = wave >> 1, wn = wave & 1;
    const int quad = lane >> 4, l15 = lane & 15, l7 = lane & 7;

    const int col0 = blockIdx.x * 128;
    const int row0 = blockIdx.y * 128;
    const int b = row0 >> 11;                        // 2048 rows per batch, tiles don't straddle
    const long Xrow0 = (long)b * SEQP + PAD + (row0 & (SEQ - 1));

    const int s_base = wave * 256 + lane;            // staging unit id (+q*64)

    f32x4 acc[4][4];
#pragma unroll
    for (int i = 0; i < 4; i++)
#pragma unroll
        for (int j = 0; j < 4; j++)
            acc[i][j] = (f32x4){0.f, 0.f, 0.f, 0.f};

    for (int g = 0; g < ngroups; g++) {
        const u16* Ab;
        if (use_h && g == 0) {
            Ab = Hbf + ((long)row0 << 10);
        } else {
            int lag = use_h ? (g - 1) : 0;
            Ab = Xpad + ((Xrow0 - lag) << 10);
        }
        const u16* Wb = W + ((long)g << 20) + ((long)col0 << 10);

        for (int k0 = 0; k0 < 1024; k0 += 64) {
            // ---- stage A and B tiles: unit s holds (row=s>>3, kc=(s&7)^(row&7)) ----
#pragma unroll
            for (int q = 0; q < 4; q++) {
                int s = s_base + q * 64;
                int row = s >> 3;
                int kc = (s & 7) ^ (row & 7);
                const u16* gA = Ab + ((long)row << 10) + k0 + kc * 8;
                const u16* gB = Wb + ((long)row << 10) + k0 + kc * 8;
                llds16(gA, &At[(wave * 256 + q * 64) * 8]);
                llds16(gB, &Bt[(wave * 256 + q * 64) * 8]);
            }
            __syncthreads();

            // ---- fragments (swizzled ds_read_b128) ----
            s16x8 af[4][2], bfr[4][2];
#pragma unroll
            for (int mi = 0; mi < 4; mi++) {
#pragma unroll
                for (int kk = 0; kk < 2; kk++) {
                    int kcu = ((kk * 4 + quad) ^ l7) << 3;
                    af[mi][kk]  = *(const s16x8*)&At[(wm * 64 + mi * 16 + l15) * 64 + kcu];
                    bfr[mi][kk] = *(const s16x8*)&Bt[(wn * 64 + mi * 16 + l15) * 64 + kcu];
                }
            }
#pragma unroll
            for (int mi = 0; mi < 4; mi++)
#pragma unroll
                for (int ni = 0; ni < 4; ni++) {
                    acc[mi][ni] = __builtin_amdgcn_mfma_f32_16x16x32_bf16(
                        af[mi][0], bfr[ni][0], acc[mi][ni], 0, 0, 0);
                    acc[mi][ni] = __builtin_amdgcn_mfma_f32_16x16x32_bf16(
                        af[mi][1], bfr[ni][1], acc[mi][ni], 0, 0, 0);
                }
            __syncthreads();
        }
    }

    // ---- epilogue: C/D layout col=lane&15, row=quad*4+reg ----
#pragma unroll
    for (int mi = 0; mi < 4; mi++) {
        int r = row0 + wm * 64 + mi * 16 + quad * 4;
#pragma unroll
        for (int ni = 0; ni < 4; ni++) {
            int c = col0 + wn * 64 + ni * 16 + l15;
            f32x4 v = acc[mi][ni];
            if (bf16_out) {
                u16* ob = (u16*)outv;
#pragma unroll
                for (int reg = 0; reg < 4; reg++)
                    ob[((long)(r + reg) << 10) + c] = f2b(v[reg]);
            } else {
                float* of = (float*)outv;
#pragma unroll
                for (int reg = 0; reg < 4; reg++)
                    of[((long)(r + reg) << 10) + c] = v[reg];
            }
        }
    }
}

// ---------------- launch ----------------

extern "C" void kernel_launch(void* const* d_in, const int* in_sizes, int n_in,
                              void* d_out, int out_size, void* d_ws, size_t ws_size,
                              hipStream_t stream) {
    const float* x  = (const float*)d_in[0];   // (4,2048,1024)
    const float* h0 = (const float*)d_in[1];   // (1024,)
    const float* A  = (const float*)d_in[2];   // (1024,)
    const float* B  = (const float*)d_in[3];   // (1024,1024)
    const float* C  = (const float*)d_in[4];   // (1024,1024)
    const float* M  = (const float*)d_in[5];   // (1024,1024,10)
    float* out = (float*)d_out;

    char* ws = (char*)d_ws;
    u16*   Xpad  = (u16*)  (ws);                      // 16,908,288
    u16*   Hbf   = (u16*)  (ws + 16908288);           // 16,777,216
    u16*   Wall  = (u16*)  (ws + 33685504);           // 23,068,672 (group0 = C^T)
    u16*   Btr   = (u16*)  (ws + 56754176);           // 2,097,152
    u16*   Ubf   = (u16*)  (ws + 58851328);           // 16,777,216
    float* F     = (float*)(ws + 75628544);           // 262,144
    float* Carry = (float*)(ws + 75890688);           // 262,144  (end ~76.2 MB)

    // fused conversions
    k_prep<<<dim3(PREP_M_END), dim3(256), 0, stream>>>(x, B, C, M, Xpad, Btr, Wall);

    // U = X @ B  (bf16 output)
    k_gemm<<<dim3(8, 64), dim3(256), 0, stream>>>(Ubf, Xpad, Xpad, Btr, 1, 0, 1);

    // chunked linear scan -> Hbf
    k_scan1<<<dim3(4, 64), dim3(256), 0, stream>>>(Ubf, A, F);
    k_scan2<<<dim3(16), dim3(256), 0, stream>>>(F, A, h0, Carry);
    k_scan3<<<dim3(4, 64), dim3(256), 0, stream>>>(Ubf, A, Carry, Hbf);

    // out = H @ C + sum_k shift_k(X) @ M_k   (11 K-groups)
    k_gemm<<<dim3(8, 64), dim3(256), 0, stream>>>(out, Xpad, Hbf, Wall, 11, 1, 0);
}

// Round 3
// 337.031 us; speedup vs baseline: 1.1392x; 1.0896x over previous
//
#include <hip/hip_runtime.h>
#include <stdint.h>

typedef unsigned short u16;
typedef __attribute__((ext_vector_type(4))) float f32x4;
typedef __attribute__((ext_vector_type(8))) short s16x8;

#define BATCH 4
#define SEQ   2048
#define DIM   1024   // D_IN = STATE = D_OUT
#define KX    10
#define PAD   16               // zero rows per batch for AR lags
#define SEQP  (SEQ+PAD)        // 2064

// fp32 -> bf16 round-to-nearest-even
__device__ __forceinline__ u16 f2b(float f) {
    union { float f; uint32_t u; } v; v.f = f;
    uint32_t u = v.u + 0x7fffu + ((v.u >> 16) & 1u);
    return (u16)(u >> 16);
}
__device__ __forceinline__ float b2f(u16 h) {
    union { uint32_t u; float f; } v; v.u = ((uint32_t)h) << 16;
    return v.f;
}

// async global->LDS, 16B per lane; lds dest is wave-uniform base (+lane*16 by HW)
__device__ __forceinline__ void llds16(const u16* g, u16* l) {
    __builtin_amdgcn_global_load_lds(
        (const __attribute__((address_space(1))) uint32_t*)g,
        (__attribute__((address_space(3))) uint32_t*)l, 16, 0, 0);
}

// ---------------- fused prep kernel ----------------
#define PREP_X_END  8256
#define PREP_C_END  10304
#define PREP_M_END  14400

__global__ __launch_bounds__(256) void k_prep(
    const float* __restrict__ x, const float* __restrict__ B,
    const float* __restrict__ C, const float* __restrict__ M,
    u16* __restrict__ Xpad, u16* __restrict__ Btr, u16* __restrict__ Wall)
{
    __shared__ float tile[32][33];
    const int bid = blockIdx.x, tid = threadIdx.x;

    if (bid < PREP_X_END) {
        // inputs (4,2048,1024) f32 -> Xpad (4,2064,1024) bf16, 16 zero rows/batch
        int idx = bid * 256 + tid;
        long e = (long)idx * 4;
        int i = (int)(e & 1023);
        int row = (int)(e >> 10);
        int t = row % SEQP;
        int b = row / SEQP;
        ushort4 o;
        if (t < PAD) {
            o.x = 0; o.y = 0; o.z = 0; o.w = 0;
        } else {
            const float4 v = *(const float4*)(x + (((long)(b * SEQ + (t - PAD)) << 10) + i));
            o.x = f2b(v.x); o.y = f2b(v.y); o.z = f2b(v.z); o.w = f2b(v.w);
        }
        *(ushort4*)(Xpad + ((long)row << 10) + i) = o;
    } else if (bid < PREP_C_END) {
        // transpose+bf16: B -> Btr, C -> Wall group 0
        const int tb = bid - PREP_X_END;
        const float* in = (tb < 1024) ? B : C;
        u16* out = (tb < 1024) ? Btr : Wall;
        int lb = tb & 1023;
        int bx = lb & 31, by = lb >> 5;
        int tx = tid & 31, ty = tid >> 5;
#pragma unroll
        for (int j = 0; j < 4; j++)
            tile[ty + j * 8][tx] = in[(long)(by * 32 + ty + j * 8) * 1024 + bx * 32 + tx];
        __syncthreads();
#pragma unroll
        for (int j = 0; j < 4; j++)
            out[(long)(bx * 32 + ty + j * 8) * 1024 + by * 32 + tx] = f2b(tile[tx][ty + j * 8]);
    } else {
        // M (o,i,k) f32 -> Wall groups 1..10 as [k][o][i] bf16
        int idx = (bid - PREP_C_END) * 256 + tid;
        int o = idx >> 10, i = idx & 1023;
        const float* src = M + (long)idx * KX;
#pragma unroll
        for (int k = 0; k < KX; k++)
            Wall[((long)(k + 1) << 20) + ((long)o << 10) + i] = f2b(src[k]);
    }
}

// ---------------- scan kernels (chunked parallel linear scan) ----------------

__global__ void k_scan1(const u16* __restrict__ U, const float* __restrict__ A,
                        float* __restrict__ F) {
    int s = blockIdx.x * 256 + threadIdx.x;
    int bc = blockIdx.y;
    int b = bc >> 4, c = bc & 15;
    float a = A[s];
    const u16* u = U + (((long)(b * SEQ + c * 128)) << 10) + s;
    float f = 0.f;
#pragma unroll 8
    for (int j = 0; j < 128; j++) f = fmaf(a, f, b2f(u[(long)j << 10]));
    F[((long)bc << 10) + s] = f;
}

__global__ void k_scan2(const float* __restrict__ F, const float* __restrict__ A,
                        const float* __restrict__ h0, float* __restrict__ Carry) {
    int idx = blockIdx.x * 256 + threadIdx.x;
    int b = idx >> 10, s = idx & 1023;
    float a = A[s];
    float a128 = a;
#pragma unroll
    for (int q = 0; q < 7; q++) a128 *= a128;
    float carry = h0[s];
#pragma unroll
    for (int c = 0; c < 16; c++) {
        long off = ((long)(b * 16 + c) << 10) + s;
        Carry[off] = carry;
        carry = fmaf(a128, carry, F[off]);
    }
}

// writes H in-place over U (same element, same thread -> no hazard)
__global__ void k_scan3(u16* __restrict__ U, const float* __restrict__ A,
                        const float* __restrict__ Carry) {
    int s = blockIdx.x * 256 + threadIdx.x;
    int bc = blockIdx.y;
    int b = bc >> 4, c = bc & 15;
    float a = A[s];
    long base = (((long)(b * SEQ + c * 128)) << 10) + s;
    float h = Carry[((long)bc << 10) + s];
#pragma unroll 8
    for (int j = 0; j < 128; j++) {
        h = fmaf(a, h, b2f(U[base + ((long)j << 10)]));
        U[base + ((long)j << 10)] = f2b(h);
    }
}

// ---------------- grouped GEMM, k-outer / g-inner with shared X slab ----------------
// out[r][n] = sum_g sum_k Aop_g[r][k] * W'[g][n][k]
// use_h=1 (11 groups): g in [0,9] -> A = Xpad rows lag g, W' = Wall group g+1 (M_g);
//                      g = 10    -> A = Hbf rows (lag 0), W' = Wall group 0 (C^T).
// use_h=0: g=0 -> A = Xpad lag 0, W' = W base (Btr).
// Per k0: stage 160-row X slab once (all lags read it), double-buffer W per group,
// H staged into the X-slab region for the last group.
__global__ __launch_bounds__(256) void k_gemm(
    void* __restrict__ outv, const u16* __restrict__ Xpad,
    const u16* __restrict__ Hbf, const u16* __restrict__ W,
    int ngroups, int use_h, int bf16_out)
{
    __shared__ u16 Asl[160 * 64];        // 20 KB X slab [Xrow0-16, Xrow0+144); H reuses [0,128)
    __shared__ u16 Wb2[2][128 * 64];     // 2 x 16 KB

    const int tid  = threadIdx.x;
    const int wave = tid >> 6, lane = tid & 63;
    const int wm = wave >> 1, wn = wave & 1;
    const int quad = lane >> 4, l15 = lane & 15, l7 = lane & 7;

    const int col0 = blockIdx.x * 128;
    const int row0 = blockIdx.y * 128;
    const int bb = row0 >> 11;
    const long Xrow0 = (long)bb * SEQP + PAD + (row0 & (SEQ - 1));
    const long XslabBase = (Xrow0 - 16) << 10;
    const int lastg = ngroups - 1;

    f32x4 acc[4][4];
#pragma unroll
    for (int i = 0; i < 4; i++)
#pragma unroll
        for (int j = 0; j < 4; j++)
            acc[i][j] = (f32x4){0.f, 0.f, 0.f, 0.f};

    for (int k0 = 0; k0 < 1024; k0 += 64) {
        // ---- stage X slab: 160 rows x 64 k, 1280 units of 16B ----
#pragma unroll
        for (int q = 0; q < 5; q++) {
            int u = wave * 320 + q * 64 + lane;
            int row = u >> 3;
            int kc = (u & 7) ^ (row & 7);
            llds16(Xpad + XslabBase + ((long)row << 10) + k0 + kc * 8,
                   &Asl[(wave * 320 + q * 64) * 8]);
        }
        // ---- stage W for g=0 into Wb2[0] ----
        {
            int wsel = use_h ? 1 : 0;
            const u16* Wg = W + ((long)wsel << 20) + ((long)col0 << 10);
#pragma unroll
            for (int q = 0; q < 4; q++) {
                int u = wave * 256 + q * 64 + lane;
                int row = u >> 3;
                int kc = (u & 7) ^ (row & 7);
                llds16(Wg + ((long)row << 10) + k0 + kc * 8,
                       &Wb2[0][(wave * 256 + q * 64) * 8]);
            }
        }
        __syncthreads();

        for (int g = 0; g < ngroups; g++) {
            const bool isH = use_h && (g == lastg);
            if (isH) {
                // X slab done (previous barrier); overwrite rows [0,128) with H
                const u16* Hb = Hbf + ((long)row0 << 10);
#pragma unroll
                for (int q = 0; q < 4; q++) {
                    int u = wave * 256 + q * 64 + lane;
                    int row = u >> 3;
                    int kc = (u & 7) ^ (row & 7);
                    llds16(Hb + ((long)row << 10) + k0 + kc * 8,
                           &Asl[(wave * 256 + q * 64) * 8]);
                }
                __syncthreads();
            }
            // ---- prefetch next W into the other buffer (drained at end-of-g barrier) ----
            if (g < lastg) {
                int gn = g + 1;
                int wsel = use_h ? ((gn == lastg) ? 0 : gn + 1) : gn;
                const u16* Wg = W + ((long)wsel << 20) + ((long)col0 << 10);
                u16* dst = Wb2[gn & 1];
#pragma unroll
                for (int q = 0; q < 4; q++) {
                    int u = wave * 256 + q * 64 + lane;
                    int row = u >> 3;
                    int kc = (u & 7) ^ (row & 7);
                    llds16(Wg + ((long)row << 10) + k0 + kc * 8,
                           &dst[(wave * 256 + q * 64) * 8]);
                }
            }

            // ---- fragments (swizzled ds_read_b128) ----
            const int rbase = isH ? 0 : (16 - g);   // slab-local row offset for this lag
            const int r7 = (l15 + rbase) & 7;
            const u16* Wrd = Wb2[g & 1];

            s16x8 af[4][2], bfr[4][2];
#pragma unroll
            for (int mi = 0; mi < 4; mi++) {
                int arow = rbase + wm * 64 + mi * 16 + l15;
#pragma unroll
                for (int kk = 0; kk < 2; kk++) {
                    int kca = ((kk * 4 + quad) ^ r7) << 3;
                    int kcb = ((kk * 4 + quad) ^ l7) << 3;
                    af[mi][kk]  = *(const s16x8*)&Asl[arow * 64 + kca];
                    bfr[mi][kk] = *(const s16x8*)&Wrd[(wn * 64 + mi * 16 + l15) * 64 + kcb];
                }
            }
#pragma unroll
            for (int mi = 0; mi < 4; mi++)
#pragma unroll
                for (int ni = 0; ni < 4; ni++) {
                    acc[mi][ni] = __builtin_amdgcn_mfma_f32_16x16x32_bf16(
                        af[mi][0], bfr[ni][0], acc[mi][ni], 0, 0, 0);
                    acc[mi][ni] = __builtin_amdgcn_mfma_f32_16x16x32_bf16(
                        af[mi][1], bfr[ni][1], acc[mi][ni], 0, 0, 0);
                }
            __syncthreads();
        }
    }

    // ---- epilogue: C/D layout col=lane&15, row=quad*4+reg ----
#pragma unroll
    for (int mi = 0; mi < 4; mi++) {
        int r = row0 + wm * 64 + mi * 16 + quad * 4;
#pragma unroll
        for (int ni = 0; ni < 4; ni++) {
            int c = col0 + wn * 64 + ni * 16 + l15;
            f32x4 v = acc[mi][ni];
            if (bf16_out) {
                u16* ob = (u16*)outv;
#pragma unroll
                for (int reg = 0; reg < 4; reg++)
                    ob[((long)(r + reg) << 10) + c] = f2b(v[reg]);
            } else {
                float* of = (float*)outv;
#pragma unroll
                for (int reg = 0; reg < 4; reg++)
                    of[((long)(r + reg) << 10) + c] = v[reg];
            }
        }
    }
}

// ---------------- launch ----------------

extern "C" void kernel_launch(void* const* d_in, const int* in_sizes, int n_in,
                              void* d_out, int out_size, void* d_ws, size_t ws_size,
                              hipStream_t stream) {
    const float* x  = (const float*)d_in[0];   // (4,2048,1024)
    const float* h0 = (const float*)d_in[1];   // (1024,)
    const float* A  = (const float*)d_in[2];   // (1024,)
    const float* B  = (const float*)d_in[3];   // (1024,1024)
    const float* C  = (const float*)d_in[4];   // (1024,1024)
    const float* M  = (const float*)d_in[5];   // (1024,1024,10)
    float* out = (float*)d_out;

    char* ws = (char*)d_ws;
    u16*   Xpad  = (u16*)  (ws);                      // 16,908,288
    u16*   Wall  = (u16*)  (ws + 16908288);           // 23,068,672 (group0 = C^T)
    u16*   Btr   = (u16*)  (ws + 39976960);           // 2,097,152
    u16*   Ubf   = (u16*)  (ws + 42074112);           // 16,777,216 (scan3 overwrites with H)
    float* F     = (float*)(ws + 58851328);           // 262,144
    float* Carry = (float*)(ws + 59113472);           // 262,144  (end ~59.4 MB)

    // fused conversions
    k_prep<<<dim3(PREP_M_END), dim3(256), 0, stream>>>(x, B, C, M, Xpad, Btr, Wall);

    // U = X @ B  (bf16 output)
    k_gemm<<<dim3(8, 64), dim3(256), 0, stream>>>(Ubf, Xpad, Ubf, Btr, 1, 0, 1);

    // chunked linear scan; scan3 turns Ubf into Hbf in-place
    k_scan1<<<dim3(4, 64), dim3(256), 0, stream>>>(Ubf, A, F);
    k_scan2<<<dim3(16), dim3(256), 0, stream>>>(F, A, h0, Carry);
    k_scan3<<<dim3(4, 64), dim3(256), 0, stream>>>(Ubf, A, Carry);

    // out = H @ C + sum_k shift_k(X) @ M_k   (11 K-groups)
    k_gemm<<<dim3(8, 64), dim3(256), 0, stream>>>(out, Xpad, Ubf, Wall, 11, 1, 0);
}